// Round 16
// baseline (597.857 us; speedup 1.0000x reference)
//
#include <hip/hip_runtime.h>

// ================= CSR build: windowed counting sort, zero global atomics =================

#define NW 8
#define WS 12512          // ceil(100000/8); 50,048 B LDS histograms
#define NSL 512           // edge slices for bucketing
#define NK 64             // slices per window for hist/place

__global__ __launch_bounds__(256) void bucket_count_kernel(const int* __restrict__ dst,
                                                           int* __restrict__ wcnt, int E) {
    __shared__ int cnt[NW];
    int tid = threadIdx.x;
    if (tid < NW) cnt[tid] = 0;
    __syncthreads();
    int sl = (E + NSL - 1) / NSL;
    int e0 = blockIdx.x * sl, e1 = e0 + sl; if (e1 > E) e1 = E;
    int lane = tid & 63;
    for (int e = e0 + tid; e < e1; e += 256) {
        int w = dst[e] / WS;
        #pragma unroll
        for (int ww = 0; ww < NW; ++ww) {
            unsigned long long m = __ballot(w == ww);
            if (m) {
                int leader = __ffsll((long long)m) - 1;
                if (lane == leader) atomicAdd(&cnt[ww], __popcll(m));
            }
        }
    }
    __syncthreads();
    if (tid < NW) wcnt[blockIdx.x * NW + tid] = cnt[tid];
}

__global__ __launch_bounds__(512) void scan_wofs_kernel(const int* __restrict__ wcnt,
                                                        int* __restrict__ wofs,
                                                        int* __restrict__ wstart, int E) {
    __shared__ int sd[512];
    __shared__ int tot[NW], wbase[NW + 1];
    int tid = threadIdx.x;
    int w = tid & 7, j = tid >> 3;
    int v[8];
    int s = 0;
    #pragma unroll
    for (int i = 0; i < 8; ++i) {
        v[i] = s;
        s += wcnt[(j * 8 + i) * NW + w];
    }
    sd[tid] = s;
    __syncthreads();
    for (int off = 8; off < 512; off <<= 1) {
        int x = (tid >= off) ? sd[tid - off] : 0;
        __syncthreads();
        sd[tid] += x;
        __syncthreads();
    }
    int excl = sd[tid] - s;
    if (j == 63) tot[w] = sd[tid];
    __syncthreads();
    if (tid == 0) {
        int run = 0;
        for (int ww = 0; ww < NW; ++ww) { wbase[ww] = run; run += tot[ww]; }
        wbase[NW] = run;
        for (int ww = 0; ww <= NW; ++ww) wstart[ww] = wbase[ww];
    }
    __syncthreads();
    int base = wbase[w] + excl;
    #pragma unroll
    for (int i = 0; i < 8; ++i) wofs[(j * 8 + i) * NW + w] = base + v[i];
}

__global__ __launch_bounds__(256) void bucket_scatter_kernel(const int* __restrict__ src,
                                                             const int* __restrict__ dst,
                                                             const int* __restrict__ wofs,
                                                             int* __restrict__ srcb,
                                                             int* __restrict__ dstb, int E) {
    __shared__ int cur[NW];
    int tid = threadIdx.x;
    if (tid < NW) cur[tid] = wofs[blockIdx.x * NW + tid];
    __syncthreads();
    int sl = (E + NSL - 1) / NSL;
    int e0 = blockIdx.x * sl, e1 = e0 + sl; if (e1 > E) e1 = E;
    int lane = tid & 63;
    for (int e = e0 + tid; e < e1; e += 256) {
        int d = dst[e];
        int s = src[e];
        int w = d / WS;
        #pragma unroll
        for (int ww = 0; ww < NW; ++ww) {
            unsigned long long m = __ballot(w == ww);
            if (w == ww) {
                int leader = __ffsll((long long)m) - 1;
                int rank = __popcll(m & ((1ull << lane) - 1));
                int base = 0;
                if (lane == leader) base = atomicAdd(&cur[ww], __popcll(m));
                base = __shfl(base, leader, 64);
                dstb[base + rank] = d;
                srcb[base + rank] = s;
            }
        }
    }
}

__global__ __launch_bounds__(256) void histpart2_kernel(const int* __restrict__ dstb,
                                                        const int* __restrict__ wstart,
                                                        int* __restrict__ part) {
    __shared__ int cnt[WS];
    int tid = threadIdx.x;
    int bid = blockIdx.x;
    int w = bid & 7, k = bid >> 3;
    int lo = w * WS;
    for (int i = tid; i < WS; i += 256) cnt[i] = 0;
    __syncthreads();
    int wb = wstart[w], we = wstart[w + 1];
    int chunk = (we - wb + NK - 1) / NK;
    int kb = wb + k * chunk, ke = kb + chunk; if (ke > we) ke = we;
    for (int e = kb + tid; e < ke; e += 256) atomicAdd(&cnt[dstb[e] - lo], 1);
    __syncthreads();
    int* pb = part + (size_t)bid * WS;
    for (int i = tid; i < WS; i += 256) pb[i] = cnt[i];
}

// fused: slice-scan of part + hist + dis + per-256-bin partials
__global__ __launch_bounds__(256) void scanslice2_kernel(int* __restrict__ part,
                                                         int* __restrict__ hist,
                                                         float* __restrict__ dis,
                                                         int* __restrict__ partials,
                                                         int N, int NB) {
    __shared__ int sdata[256];
    int t = threadIdx.x;
    int bin = blockIdx.x * 256 + t;
    int run = 0;
    if (bin < NB) {
        int w = bin / WS;
        int i = bin - w * WS;
        for (int k = 0; k < NK; ++k) {
            size_t idx = (size_t)((k << 3) + w) * WS + i;
            int v = part[idx];
            part[idx] = run;
            run += v;
        }
    }
    if (bin < N) {
        hist[bin] = run;
        dis[bin] = 1.0f / sqrtf((float)(run + 1));   // +1 self-loop
    }
    sdata[t] = (bin < N) ? run : 0;
    __syncthreads();
    for (int off = 128; off > 0; off >>= 1) {
        if (t < off) sdata[t] += sdata[t + off];
        __syncthreads();
    }
    if (t == 0) partials[blockIdx.x] = sdata[0];
}

__global__ __launch_bounds__(1024) void scan_top_kernel(int* __restrict__ partials, int nb) {
    __shared__ int sdata[1024];
    int t = threadIdx.x;
    int v = (t < nb) ? partials[t] : 0;
    sdata[t] = v;
    __syncthreads();
    for (int off = 1; off < 1024; off <<= 1) {
        int x = (t >= off) ? sdata[t - off] : 0;
        __syncthreads();
        sdata[t] += x;
        __syncthreads();
    }
    if (t < nb) partials[t] = sdata[t] - v;  // exclusive
}

__global__ __launch_bounds__(256) void scan_final_kernel(const int* __restrict__ hist,
                                                         const int* __restrict__ partials,
                                                         int* __restrict__ row_ptr, int n) {
    __shared__ int sdata[256];
    int i = blockIdx.x * 256 + threadIdx.x;
    int t = threadIdx.x;
    int v = (i < n) ? hist[i] : 0;
    sdata[t] = v;
    __syncthreads();
    for (int off = 1; off < 256; off <<= 1) {
        int x = (t >= off) ? sdata[t - off] : 0;
        __syncthreads();
        sdata[t] += x;
        __syncthreads();
    }
    int base = partials[blockIdx.x];
    if (i < n) row_ptr[i] = base + sdata[t] - v;  // exclusive
    if (i == n - 1) row_ptr[n] = base + sdata[t]; // total = E
}

__global__ __launch_bounds__(256) void place2_kernel(const int* __restrict__ srcb,
                                                     const int* __restrict__ dstb,
                                                     const int* __restrict__ wstart,
                                                     const int* __restrict__ row_ptr,
                                                     const int* __restrict__ part,
                                                     int* __restrict__ src_sorted) {
    __shared__ int cnt[WS];
    int tid = threadIdx.x;
    int bid = blockIdx.x;
    int w = bid & 7, k = bid >> 3;
    int lo = w * WS;
    for (int i = tid; i < WS; i += 256) cnt[i] = 0;
    __syncthreads();
    int wb = wstart[w], we = wstart[w + 1];
    int chunk = (we - wb + NK - 1) / NK;
    int kb = wb + k * chunk, ke = kb + chunk; if (ke > we) ke = we;
    const int* pb = part + (size_t)bid * WS;
    for (int e = kb + tid; e < ke; e += 256) {
        int d = dstb[e];
        int od = d - lo;
        int r = atomicAdd(&cnt[od], 1);
        src_sorted[row_ptr[d] + pb[od] + r] = srcb[e];
    }
}

// ---------------- layer-1 matmul: Ad[n] = dis[n] * (x[n] @ W0) ----------------
// 16-row tile: the tile's x-span (16*495 floats) is contiguous and float4-aligned
// -> staging is a pure float4 identity copy (R4 lesson: sequential, 16B loads).
// W0 (495x16 = 31.7 KB) is ALSO staged to LDS (fixes R4's per-FMA global-W0
// latency chain). Full K in one pass: no K-split, no Apart, no reduce pass.
// Grid 6250 blocks = 24.4/CU (perfect balance); 63.5 KB LDS -> 2 blocks/CU.
// LDS reads: xs[r*495+k] -> 4 distinct banks (495%32=15) x 16-lane broadcast;
// wsh[k*16+j] -> 16 consecutive banks x 4-broadcast. Both conflict-free.

__global__ __launch_bounds__(256) void mm0_kernel(const float* __restrict__ x,
                                                  const float* __restrict__ W0,
                                                  const float* __restrict__ dis,
                                                  float* __restrict__ Ad, int N, int in_ch) {
    extern __shared__ float lds[];
    float* xs  = lds;                 // 16*in_ch floats
    float* wsh = lds + 16 * in_ch;    // in_ch*16 floats
    int tid = threadIdx.x;
    long n0 = (long)blockIdx.x * 16;

    int nfloat = 16 * in_ch;          // 7920, divisible by 4
    if ((nfloat & 3) == 0) {
        const float4* gx = (const float4*)(x + n0 * in_ch);
        const float4* gw = (const float4*)W0;
        float4* lx = (float4*)xs;
        float4* lw = (float4*)wsh;
        int nf4 = nfloat >> 2;        // 1980
        for (int o = tid; o < nf4; o += 256) {
            lx[o] = gx[o];
            lw[o] = gw[o];
        }
    } else {
        for (int o = tid; o < nfloat; o += 256) {
            xs[o] = x[n0 * in_ch + o];
            wsh[o] = W0[o];
        }
    }
    __syncthreads();

    int r = tid >> 4, j = tid & 15;
    const float* xrow = xs + r * in_ch;
    float acc0 = 0.f, acc1 = 0.f;
    int k = 0;
    for (; k + 8 <= in_ch; k += 8) {
        #pragma unroll
        for (int u = 0; u < 8; u += 2) {
            acc0 = fmaf(xrow[k + u],     wsh[(k + u) * 16 + j],     acc0);
            acc1 = fmaf(xrow[k + u + 1], wsh[(k + u + 1) * 16 + j], acc1);
        }
    }
    for (; k < in_ch; ++k) acc0 = fmaf(xrow[k], wsh[k * 16 + j], acc0);

    long node = n0 + r;
    if (node < N) Ad[node * 16 + j] = dis[node] * (acc0 + acc1);
}

// ---------------- fused propagation + next-layer matmul ----------------

__global__ __launch_bounds__(256) void prop_mm_kernel(const float* __restrict__ Ad,
                                                      const float* __restrict__ dis,
                                                      const int* __restrict__ row_ptr,
                                                      const int* __restrict__ src_sorted,
                                                      const float* __restrict__ bias,
                                                      const float* __restrict__ Wn,
                                                      float* __restrict__ Adout, int N) {
    __shared__ float Wsh[256];
    __shared__ float rowbuf[4][16];
    int tid = threadIdx.x;
    Wsh[tid] = Wn[tid];
    int wv = tid >> 6, lane = tid & 63;
    int wid = (blockIdx.x << 2) + wv;
    bool act = wid < N;
    int j4 = lane & 3, q = lane >> 2;
    float4 acc = make_float4(0.f, 0.f, 0.f, 0.f);
    float dn = 0.f;
    float4 self = make_float4(0.f, 0.f, 0.f, 0.f);
    float4 b4 = make_float4(0.f, 0.f, 0.f, 0.f);
    if (act) {
        int start = row_ptr[wid], end = row_ptr[wid + 1];
        for (int e = start + q; e < end; e += 16) {
            int s = src_sorted[e];
            float4 v = *(const float4*)(Ad + (size_t)s * 16 + j4 * 4);
            acc.x += v.x; acc.y += v.y; acc.z += v.z; acc.w += v.w;
        }
        dn = dis[wid];
        self = *(const float4*)(Ad + (size_t)wid * 16 + j4 * 4);
        b4 = *(const float4*)(bias + j4 * 4);
    }
    #pragma unroll
    for (int m = 4; m <= 32; m <<= 1) {
        acc.x += __shfl_xor(acc.x, m);
        acc.y += __shfl_xor(acc.y, m);
        acc.z += __shfl_xor(acc.z, m);
        acc.w += __shfl_xor(acc.w, m);
    }
    float4 h;
    h.x = fmaxf(fmaf(dn, acc.x + self.x, b4.x), 0.f);
    h.y = fmaxf(fmaf(dn, acc.y + self.y, b4.y), 0.f);
    h.z = fmaxf(fmaf(dn, acc.z + self.z, b4.z), 0.f);
    h.w = fmaxf(fmaf(dn, acc.w + self.w, b4.w), 0.f);
    __syncthreads();
    if (act && q == 0) *(float4*)&rowbuf[wv][j4 * 4] = h;
    __syncthreads();
    if (act && q == 0) {
        int jb = j4 * 4;
        float o0 = 0.f, o1 = 0.f, o2 = 0.f, o3 = 0.f;
        #pragma unroll
        for (int k = 0; k < 16; ++k) {
            float hv = rowbuf[wv][k];
            o0 = fmaf(hv, Wsh[k * 16 + jb + 0], o0);
            o1 = fmaf(hv, Wsh[k * 16 + jb + 1], o1);
            o2 = fmaf(hv, Wsh[k * 16 + jb + 2], o2);
            o3 = fmaf(hv, Wsh[k * 16 + jb + 3], o3);
        }
        *(float4*)(Adout + (size_t)wid * 16 + jb) =
            make_float4(dn * o0, dn * o1, dn * o2, dn * o3);
    }
}

// last layer: h3 -> U = h3 @ Wf0_top, V = h3 @ Wf0_bot + bf0
__global__ __launch_bounds__(256) void prop_uv_kernel(const float* __restrict__ Ad,
                                                      const float* __restrict__ dis,
                                                      const int* __restrict__ row_ptr,
                                                      const int* __restrict__ src_sorted,
                                                      const float* __restrict__ bias,
                                                      const float* __restrict__ Wf0,
                                                      const float* __restrict__ bf0,
                                                      float* __restrict__ U,
                                                      float* __restrict__ V, int N) {
    __shared__ float Wsh[512];
    __shared__ float bfsh[16];
    __shared__ float rowbuf[4][16];
    int tid = threadIdx.x;
    Wsh[tid] = Wf0[tid];
    Wsh[256 + tid] = Wf0[256 + tid];
    if (tid < 16) bfsh[tid] = bf0[tid];
    int wv = tid >> 6, lane = tid & 63;
    int wid = (blockIdx.x << 2) + wv;
    bool act = wid < N;
    int j4 = lane & 3, q = lane >> 2;
    float4 acc = make_float4(0.f, 0.f, 0.f, 0.f);
    float dn = 0.f;
    float4 self = make_float4(0.f, 0.f, 0.f, 0.f);
    float4 b4 = make_float4(0.f, 0.f, 0.f, 0.f);
    if (act) {
        int start = row_ptr[wid], end = row_ptr[wid + 1];
        for (int e = start + q; e < end; e += 16) {
            int s = src_sorted[e];
            float4 v = *(const float4*)(Ad + (size_t)s * 16 + j4 * 4);
            acc.x += v.x; acc.y += v.y; acc.z += v.z; acc.w += v.w;
        }
        dn = dis[wid];
        self = *(const float4*)(Ad + (size_t)wid * 16 + j4 * 4);
        b4 = *(const float4*)(bias + j4 * 4);
    }
    #pragma unroll
    for (int m = 4; m <= 32; m <<= 1) {
        acc.x += __shfl_xor(acc.x, m);
        acc.y += __shfl_xor(acc.y, m);
        acc.z += __shfl_xor(acc.z, m);
        acc.w += __shfl_xor(acc.w, m);
    }
    float4 h;
    h.x = fmaxf(fmaf(dn, acc.x + self.x, b4.x), 0.f);
    h.y = fmaxf(fmaf(dn, acc.y + self.y, b4.y), 0.f);
    h.z = fmaxf(fmaf(dn, acc.z + self.z, b4.z), 0.f);
    h.w = fmaxf(fmaf(dn, acc.w + self.w, b4.w), 0.f);
    __syncthreads();
    if (act && q == 0) *(float4*)&rowbuf[wv][j4 * 4] = h;
    __syncthreads();
    if (act && q == 0) {
        int jb = j4 * 4;
        float u0 = 0.f, u1 = 0.f, u2 = 0.f, u3 = 0.f;
        float v0 = 0.f, v1 = 0.f, v2 = 0.f, v3 = 0.f;
        #pragma unroll
        for (int k = 0; k < 16; ++k) {
            float hv = rowbuf[wv][k];
            u0 = fmaf(hv, Wsh[k * 16 + jb + 0], u0);
            u1 = fmaf(hv, Wsh[k * 16 + jb + 1], u1);
            u2 = fmaf(hv, Wsh[k * 16 + jb + 2], u2);
            u3 = fmaf(hv, Wsh[k * 16 + jb + 3], u3);
            v0 = fmaf(hv, Wsh[256 + k * 16 + jb + 0], v0);
            v1 = fmaf(hv, Wsh[256 + k * 16 + jb + 1], v1);
            v2 = fmaf(hv, Wsh[256 + k * 16 + jb + 2], v2);
            v3 = fmaf(hv, Wsh[256 + k * 16 + jb + 3], v3);
        }
        *(float4*)(U + (size_t)wid * 16 + jb) = make_float4(u0, u1, u2, u3);
        *(float4*)(V + (size_t)wid * 16 + jb) =
            make_float4(v0 + bfsh[jb + 0], v1 + bfsh[jb + 1], v2 + bfsh[jb + 2], v3 + bfsh[jb + 3]);
    }
}

// ---------------- edge head ----------------

__global__ __launch_bounds__(256) void head2_kernel(const float* __restrict__ U,
                                                    const float* __restrict__ V,
                                                    const int* __restrict__ src,
                                                    const int* __restrict__ dst,
                                                    const float* __restrict__ Wf1,
                                                    const float* __restrict__ bf1,
                                                    float* __restrict__ out, int E) {
    __shared__ float w1[16];
    __shared__ float b1s;
    int tid = threadIdx.x;
    if (tid < 16) w1[tid] = Wf1[tid];
    if (tid == 16) b1s = bf1[0];
    __syncthreads();
    int e = blockIdx.x * 256 + tid;
    if (e >= E) return;
    int s = src[e], d = dst[e];
    const float4* us = (const float4*)(U + (size_t)s * 16);
    const float4* vd = (const float4*)(V + (size_t)d * 16);
    float o = b1s;
    #pragma unroll
    for (int i = 0; i < 4; ++i) {
        float4 u = us[i];
        float4 v = vd[i];
        o = fmaf(fmaxf(u.x + v.x, 0.f), w1[i * 4 + 0], o);
        o = fmaf(fmaxf(u.y + v.y, 0.f), w1[i * 4 + 1], o);
        o = fmaf(fmaxf(u.z + v.z, 0.f), w1[i * 4 + 2], o);
        o = fmaf(fmaxf(u.w + v.w, 0.f), w1[i * 4 + 3], o);
    }
    out[e] = o;
}

// ---------------- launch ----------------

extern "C" void kernel_launch(void* const* d_in, const int* in_sizes, int n_in,
                              void* d_out, int out_size, void* d_ws, size_t ws_size,
                              hipStream_t stream) {
    const float* x   = (const float*)d_in[0];
    const int*   ei  = (const int*)d_in[1];
    const float* W0  = (const float*)d_in[2];
    const float* b0  = (const float*)d_in[3];
    const float* W1  = (const float*)d_in[4];
    const float* b1  = (const float*)d_in[5];
    const float* W2  = (const float*)d_in[6];
    const float* b2  = (const float*)d_in[7];
    const float* Wf0 = (const float*)d_in[8];
    const float* bf0 = (const float*)d_in[9];
    const float* Wf1 = (const float*)d_in[10];
    const float* bf1 = (const float*)d_in[11];

    const int H  = 16;
    const int IN = in_sizes[2] / H;        // 495
    const int N  = in_sizes[0] / IN;       // 100000
    const int E  = in_sizes[1] / 2;        // 3200000
    const int NB = NW * WS;                // 100096 padded bins
    const int* src = ei;
    const int* dst = ei + E;

    char* ws = (char*)d_ws;
    size_t off = 0;
    auto alloc = [&](size_t bytes) {
        void* p = ws + off;
        off = (off + bytes + 255) & ~size_t(255);
        return p;
    };
    int*   hist       = (int*)alloc((size_t)N * 4);
    int*   row_ptr    = (int*)alloc((size_t)(N + 1) * 4);
    int*   partials   = (int*)alloc((size_t)((NB + 255) / 256) * 4);
    float* dis        = (float*)alloc((size_t)N * 4);
    int*   src_sorted = (int*)alloc((size_t)E * 4);
    int*   part       = (int*)alloc((size_t)NW * NK * WS * 4);
    int*   wcnt       = (int*)alloc((size_t)NSL * NW * 4);
    int*   wofs       = (int*)alloc((size_t)NSL * NW * 4);
    int*   wstart     = (int*)alloc((size_t)(NW + 1) * 4);
    float* Ad         = (float*)alloc((size_t)N * 16 * 4);
    float* Ad2        = (float*)alloc((size_t)N * 16 * 4);
    float* U          = (float*)alloc((size_t)N * 16 * 4);
    float* V          = (float*)alloc((size_t)N * 16 * 4);
    int*   srcb       = (int*)alloc((size_t)E * 4);
    int*   dstb       = (int*)alloc((size_t)E * 4);

    int gE = (E + 255) / 256;
    int gN = (N + 255) / 256;
    int gNB = (NB + 255) / 256;   // == gN == 391 for these sizes

    // CSR build (no global atomics)
    bucket_count_kernel<<<NSL, 256, 0, stream>>>(dst, wcnt, E);
    scan_wofs_kernel<<<1, 512, 0, stream>>>(wcnt, wofs, wstart, E);
    bucket_scatter_kernel<<<NSL, 256, 0, stream>>>(src, dst, wofs, srcb, dstb, E);
    histpart2_kernel<<<NW * NK, 256, 0, stream>>>(dstb, wstart, part);
    scanslice2_kernel<<<gNB, 256, 0, stream>>>(part, hist, dis, partials, N, NB);
    scan_top_kernel<<<1, 1024, 0, stream>>>(partials, gN);
    scan_final_kernel<<<gN, 256, 0, stream>>>(hist, partials, row_ptr, N);
    place2_kernel<<<NW * NK, 256, 0, stream>>>(srcb, dstb, wstart, row_ptr, part, src_sorted);

    // mm0: 16-row flat-float4 tiles, W0 in LDS, full K, dis folded
    size_t mm0_lds = (size_t)(16 * IN + IN * 16) * 4;   // 63,360 B
    mm0_kernel<<<(N + 15) / 16, 256, mm0_lds, stream>>>(x, W0, dis, Ad, N, IN);

    int gP = (N + 3) / 4;
    prop_mm_kernel<<<gP, 256, 0, stream>>>(Ad, dis, row_ptr, src_sorted, b0, W1, Ad2, N);
    prop_mm_kernel<<<gP, 256, 0, stream>>>(Ad2, dis, row_ptr, src_sorted, b1, W2, Ad, N);
    prop_uv_kernel<<<gP, 256, 0, stream>>>(Ad, dis, row_ptr, src_sorted, b2, Wf0, bf0, U, V, N);

    head2_kernel<<<gE, 256, 0, stream>>>(U, V, src, dst, Wf1, bf1, (float*)d_out, E);
}

// Round 17
// 464.748 us; speedup vs baseline: 1.2864x; 1.2864x over previous
//
#include <hip/hip_runtime.h>

// ================= CSR build: windowed counting sort, zero global atomics =================

#define NW 8
#define WS 12512          // ceil(100000/8); 50,048 B LDS histograms
#define NSL 512           // edge slices for bucketing
#define NK 32             // slices per window for hist/place

__global__ __launch_bounds__(256) void bucket_count_kernel(const int* __restrict__ dst,
                                                           int* __restrict__ wcnt, int E) {
    __shared__ int cnt[NW];
    int tid = threadIdx.x;
    if (tid < NW) cnt[tid] = 0;
    __syncthreads();
    int sl = (E + NSL - 1) / NSL;
    int e0 = blockIdx.x * sl, e1 = e0 + sl; if (e1 > E) e1 = E;
    int lane = tid & 63;
    for (int e = e0 + tid; e < e1; e += 256) {
        int w = dst[e] / WS;
        #pragma unroll
        for (int ww = 0; ww < NW; ++ww) {
            unsigned long long m = __ballot(w == ww);
            if (m) {
                int leader = __ffsll((long long)m) - 1;
                if (lane == leader) atomicAdd(&cnt[ww], __popcll(m));
            }
        }
    }
    __syncthreads();
    if (tid < NW) wcnt[blockIdx.x * NW + tid] = cnt[tid];
}

// parallel scan of wcnt[512][8] along slices for each window; one 512-thread block
__global__ __launch_bounds__(512) void scan_wofs_kernel(const int* __restrict__ wcnt,
                                                        int* __restrict__ wofs,
                                                        int* __restrict__ wstart, int E) {
    __shared__ int sd[512];
    __shared__ int tot[NW], wbase[NW + 1];
    int tid = threadIdx.x;
    int w = tid & 7, j = tid >> 3;            // j: 64 groups of 8 slices
    int v[8];
    int s = 0;
    #pragma unroll
    for (int i = 0; i < 8; ++i) {
        v[i] = s;
        s += wcnt[(j * 8 + i) * NW + w];
    }
    sd[tid] = s;
    __syncthreads();
    for (int off = 8; off < 512; off <<= 1) {   // offset in tid units = 1 j-step
        int x = (tid >= off) ? sd[tid - off] : 0;
        __syncthreads();
        sd[tid] += x;
        __syncthreads();
    }
    int excl = sd[tid] - s;                    // exclusive prefix over j within window
    if (j == 63) tot[w] = sd[tid];             // window total
    __syncthreads();
    if (tid == 0) {
        int run = 0;
        for (int ww = 0; ww < NW; ++ww) { wbase[ww] = run; run += tot[ww]; }
        wbase[NW] = run;                       // == E
        for (int ww = 0; ww <= NW; ++ww) wstart[ww] = wbase[ww];
    }
    __syncthreads();
    int base = wbase[w] + excl;
    #pragma unroll
    for (int i = 0; i < 8; ++i) wofs[(j * 8 + i) * NW + w] = base + v[i];
}

__global__ __launch_bounds__(256) void bucket_scatter_kernel(const int* __restrict__ src,
                                                             const int* __restrict__ dst,
                                                             const int* __restrict__ wofs,
                                                             int* __restrict__ srcb,
                                                             int* __restrict__ dstb, int E) {
    __shared__ int cur[NW];
    int tid = threadIdx.x;
    if (tid < NW) cur[tid] = wofs[blockIdx.x * NW + tid];
    __syncthreads();
    int sl = (E + NSL - 1) / NSL;
    int e0 = blockIdx.x * sl, e1 = e0 + sl; if (e1 > E) e1 = E;
    int lane = tid & 63;
    for (int e = e0 + tid; e < e1; e += 256) {
        int d = dst[e];
        int s = src[e];
        int w = d / WS;
        #pragma unroll
        for (int ww = 0; ww < NW; ++ww) {
            unsigned long long m = __ballot(w == ww);
            if (w == ww) {
                int leader = __ffsll((long long)m) - 1;
                int rank = __popcll(m & ((1ull << lane) - 1));
                int base = 0;
                if (lane == leader) base = atomicAdd(&cur[ww], __popcll(m));
                base = __shfl(base, leader, 64);
                dstb[base + rank] = d;
                srcb[base + rank] = s;
            }
        }
    }
}

__global__ __launch_bounds__(256) void histpart2_kernel(const int* __restrict__ dstb,
                                                        const int* __restrict__ wstart,
                                                        int* __restrict__ part) {
    __shared__ int cnt[WS];
    int tid = threadIdx.x;
    int bid = blockIdx.x;
    int w = bid & 7, k = bid >> 3;
    int lo = w * WS;
    for (int i = tid; i < WS; i += 256) cnt[i] = 0;
    __syncthreads();
    int wb = wstart[w], we = wstart[w + 1];
    int chunk = (we - wb + NK - 1) / NK;
    int kb = wb + k * chunk, ke = kb + chunk; if (ke > we) ke = we;
    for (int e = kb + tid; e < ke; e += 256) atomicAdd(&cnt[dstb[e] - lo], 1);
    __syncthreads();
    int* pb = part + (size_t)bid * WS;
    for (int i = tid; i < WS; i += 256) pb[i] = cnt[i];
}

__global__ __launch_bounds__(256) void scanslice2_kernel(int* __restrict__ part,
                                                         int* __restrict__ hist, int N, int NB) {
    int bin = blockIdx.x * 256 + threadIdx.x;
    if (bin >= NB) return;
    int w = bin / WS;
    int i = bin - w * WS;
    int run = 0;
    for (int k = 0; k < NK; ++k) {
        size_t idx = (size_t)((k << 3) + w) * WS + i;
        int v = part[idx];
        part[idx] = run;
        run += v;
    }
    if (bin < N) hist[bin] = run;
}

__global__ __launch_bounds__(256) void place2_kernel(const int* __restrict__ srcb,
                                                     const int* __restrict__ dstb,
                                                     const int* __restrict__ wstart,
                                                     const int* __restrict__ row_ptr,
                                                     const int* __restrict__ part,
                                                     int* __restrict__ src_sorted) {
    __shared__ int cnt[WS];
    int tid = threadIdx.x;
    int bid = blockIdx.x;
    int w = bid & 7, k = bid >> 3;
    int lo = w * WS;
    for (int i = tid; i < WS; i += 256) cnt[i] = 0;
    __syncthreads();
    int wb = wstart[w], we = wstart[w + 1];
    int chunk = (we - wb + NK - 1) / NK;
    int kb = wb + k * chunk, ke = kb + chunk; if (ke > we) ke = we;
    const int* pb = part + (size_t)bid * WS;
    for (int e = kb + tid; e < ke; e += 256) {
        int d = dstb[e];
        int od = d - lo;
        int r = atomicAdd(&cnt[od], 1);
        src_sorted[row_ptr[d] + pb[od] + r] = srcb[e];
    }
}

// ---------------- degree / norm ----------------

__global__ __launch_bounds__(256) void dis_kernel(const int* __restrict__ hist,
                                                  float* __restrict__ dis, int N) {
    int n = blockIdx.x * 256 + threadIdx.x;
    if (n < N) dis[n] = 1.0f / sqrtf((float)(hist[n] + 1));  // +1 self-loop; deg>=1
}

// ---------------- row_ptr scan ----------------

__global__ __launch_bounds__(256) void scan_part_kernel(const int* __restrict__ hist,
                                                        int* __restrict__ partials, int n) {
    __shared__ int sdata[256];
    int i = blockIdx.x * 256 + threadIdx.x;
    int t = threadIdx.x;
    sdata[t] = (i < n) ? hist[i] : 0;
    __syncthreads();
    for (int off = 128; off > 0; off >>= 1) {
        if (t < off) sdata[t] += sdata[t + off];
        __syncthreads();
    }
    if (t == 0) partials[blockIdx.x] = sdata[0];
}

__global__ __launch_bounds__(1024) void scan_top_kernel(int* __restrict__ partials, int nb) {
    __shared__ int sdata[1024];
    int t = threadIdx.x;
    int v = (t < nb) ? partials[t] : 0;
    sdata[t] = v;
    __syncthreads();
    for (int off = 1; off < 1024; off <<= 1) {
        int x = (t >= off) ? sdata[t - off] : 0;
        __syncthreads();
        sdata[t] += x;
        __syncthreads();
    }
    if (t < nb) partials[t] = sdata[t] - v;  // exclusive
}

__global__ __launch_bounds__(256) void scan_final_kernel(const int* __restrict__ hist,
                                                         const int* __restrict__ partials,
                                                         int* __restrict__ row_ptr, int n) {
    __shared__ int sdata[256];
    int i = blockIdx.x * 256 + threadIdx.x;
    int t = threadIdx.x;
    int v = (i < n) ? hist[i] : 0;
    sdata[t] = v;
    __syncthreads();
    for (int off = 1; off < 256; off <<= 1) {
        int x = (t >= off) ? sdata[t - off] : 0;
        __syncthreads();
        sdata[t] += x;
        __syncthreads();
    }
    int base = partials[blockIdx.x];
    if (i < n) row_ptr[i] = base + sdata[t] - v;  // exclusive
    if (i == n - 1) row_ptr[n] = base + sdata[t]; // total = E
}

// ---------------- layer-1 matmul: Apart[q][N][16] = x[:, kq] @ W0[kq, :] ----------------
// Best measured config (R12): 128-row tile, K-split x4 -> 3128 blocks = 12.2/CU,
// 2-deep reg->LDS pipeline.

#define MM0_TM 128
#define MM0_KS 32

__global__ __launch_bounds__(256) void mm0_kernel(const float* __restrict__ x,
                                                  const float* __restrict__ W0,
                                                  float* __restrict__ Apart, int N, int in_ch) {
    __shared__ float xs[2][MM0_TM][33];
    __shared__ float wsh[2][MM0_KS][16];
    int tid = threadIdx.x;
    int q = blockIdx.y;
    long n0 = (long)blockIdx.x * MM0_TM;

    int kc = ((in_ch + 3) >> 2) & ~3;            // 124 (multiple of 4)
    int kbeg = q * kc;
    int kend = (q == 3) ? in_ch : kbeg + kc;
    int nsteps = (kend - kbeg + MM0_KS - 1) / MM0_KS;

    int tn = tid >> 2, tj = tid & 3;
    float acc[2][4] = {};
    float xreg[16];
    float wreg[2];

    {
        int k0 = kbeg;
        #pragma unroll
        for (int it = 0; it < 16; ++it) {
            int idx = (it << 8) + tid;
            int nn = idx >> 5, kk = idx & 31;
            long node = n0 + nn;
            int k = k0 + kk;
            xreg[it] = (node < N && k < kend) ? x[node * (long)in_ch + k] : 0.f;
        }
        #pragma unroll
        for (int it = 0; it < 2; ++it) {
            int idx = (it << 8) + tid;
            int kk = idx >> 4, j = idx & 15;
            int k = k0 + kk;
            wreg[it] = (k < kend) ? W0[k * 16 + j] : 0.f;
        }
    }

    int cur = 0;
    for (int step = 0; step < nsteps; ++step) {
        #pragma unroll
        for (int it = 0; it < 16; ++it) {
            int idx = (it << 8) + tid;
            xs[cur][idx >> 5][idx & 31] = xreg[it];
        }
        #pragma unroll
        for (int it = 0; it < 2; ++it) {
            int idx = (it << 8) + tid;
            wsh[cur][idx >> 4][idx & 15] = wreg[it];
        }
        __syncthreads();

        if (step + 1 < nsteps) {
            int k0 = kbeg + (step + 1) * MM0_KS;
            #pragma unroll
            for (int it = 0; it < 16; ++it) {
                int idx = (it << 8) + tid;
                int nn = idx >> 5, kk = idx & 31;
                long node = n0 + nn;
                int k = k0 + kk;
                xreg[it] = (node < N && k < kend) ? x[node * (long)in_ch + k] : 0.f;
            }
            #pragma unroll
            for (int it = 0; it < 2; ++it) {
                int idx = (it << 8) + tid;
                int kk = idx >> 4, j = idx & 15;
                int k = k0 + kk;
                wreg[it] = (k < kend) ? W0[k * 16 + j] : 0.f;
            }
        }

        #pragma unroll
        for (int kk = 0; kk < MM0_KS; ++kk) {
            float4 wr = *(const float4*)&wsh[cur][kk][tj * 4];
            float x0 = xs[cur][tn * 2 + 0][kk];
            float x1 = xs[cur][tn * 2 + 1][kk];
            acc[0][0] = fmaf(x0, wr.x, acc[0][0]);
            acc[0][1] = fmaf(x0, wr.y, acc[0][1]);
            acc[0][2] = fmaf(x0, wr.z, acc[0][2]);
            acc[0][3] = fmaf(x0, wr.w, acc[0][3]);
            acc[1][0] = fmaf(x1, wr.x, acc[1][0]);
            acc[1][1] = fmaf(x1, wr.y, acc[1][1]);
            acc[1][2] = fmaf(x1, wr.z, acc[1][2]);
            acc[1][3] = fmaf(x1, wr.w, acc[1][3]);
        }
        cur ^= 1;
    }

    float* outb = Apart + (size_t)q * N * 16;
    #pragma unroll
    for (int i = 0; i < 2; ++i) {
        long node = n0 + tn * 2 + i;
        if (node < N) {
            *(float4*)(outb + node * 16 + tj * 4) =
                make_float4(acc[i][0], acc[i][1], acc[i][2], acc[i][3]);
        }
    }
}

// sum the 4 K-slices AND fold in dis[node]: Ad[n][j] = dis[n] * sum_q Apart[q][n][j]
__global__ __launch_bounds__(256) void reduce4_scale_kernel(const float* __restrict__ Ap,
                                                            const float* __restrict__ dis,
                                                            float* __restrict__ Ad,
                                                            int nq, int stride4) {
    int i = blockIdx.x * 256 + threadIdx.x;
    if (i >= nq) return;
    const float4* p = (const float4*)Ap;
    float4 a = p[i];
    float4 b = p[i + stride4];
    float4 c = p[i + 2 * stride4];
    float4 d = p[i + 3 * stride4];
    float s = dis[i >> 2];
    ((float4*)Ad)[i] = make_float4(s * (a.x + b.x + c.x + d.x), s * (a.y + b.y + c.y + d.y),
                                   s * (a.z + b.z + c.z + d.z), s * (a.w + b.w + c.w + d.w));
}

// ---------------- small matmul + dis fold: Ad[n][j] = dis[n] * (Hin[n] @ W)[j] ----------------

__global__ __launch_bounds__(256) void mm16_scale_kernel(const float* __restrict__ Hin,
                                                         const float* __restrict__ W,
                                                         const float* __restrict__ dis,
                                                         float* __restrict__ Ad, int N) {
    __shared__ float ws[256];
    ws[threadIdx.x] = W[threadIdx.x];
    __syncthreads();
    int t = blockIdx.x * 256 + threadIdx.x;
    int n = t >> 4, j = t & 15;
    if (n >= N) return;
    const float* hrow = Hin + n * 16;
    float acc = 0.f;
    #pragma unroll
    for (int k = 0; k < 16; ++k) acc = fmaf(hrow[k], ws[k * 16 + j], acc);
    Ad[n * 16 + j] = dis[n] * acc;
}

// ---------------- pull propagation ----------------
// Ad[s] = dis[s]*h[s] (pre-folded): B[n] = relu(dn*(sum_e Ad[s] + Ad[n]) + b).
// Lane map: 16 edge slots x 4 float4 row-chunks -> 16 edges (1 KB) in flight per
// wave instruction; slot-reduce via shfl_xor over bits 2..5; lanes 0..3 write.

__global__ __launch_bounds__(256) void prop_kernel(const float* __restrict__ Ad,
                                                   const float* __restrict__ dis,
                                                   const int* __restrict__ row_ptr,
                                                   const int* __restrict__ src_sorted,
                                                   const float* __restrict__ bias,
                                                   float* __restrict__ B, int N) {
    int wid = (blockIdx.x << 2) + (threadIdx.x >> 6);
    if (wid >= N) return;
    int lane = threadIdx.x & 63;
    int j4 = lane & 3, q = lane >> 2;
    int start = row_ptr[wid], end = row_ptr[wid + 1];
    float4 acc = make_float4(0.f, 0.f, 0.f, 0.f);
    for (int e = start + q; e < end; e += 16) {
        int s = src_sorted[e];
        float4 v = *(const float4*)(Ad + (size_t)s * 16 + j4 * 4);
        acc.x += v.x; acc.y += v.y; acc.z += v.z; acc.w += v.w;
    }
    #pragma unroll
    for (int m = 4; m <= 32; m <<= 1) {
        acc.x += __shfl_xor(acc.x, m);
        acc.y += __shfl_xor(acc.y, m);
        acc.z += __shfl_xor(acc.z, m);
        acc.w += __shfl_xor(acc.w, m);
    }
    if (q == 0) {
        float dn = dis[wid];
        float4 self = *(const float4*)(Ad + (size_t)wid * 16 + j4 * 4);
        float4 b4 = *(const float4*)(bias + j4 * 4);
        float4 o;
        o.x = fmaxf(fmaf(dn, acc.x + self.x, b4.x), 0.f);
        o.y = fmaxf(fmaf(dn, acc.y + self.y, b4.y), 0.f);
        o.z = fmaxf(fmaf(dn, acc.z + self.z, b4.z), 0.f);
        o.w = fmaxf(fmaf(dn, acc.w + self.w, b4.w), 0.f);
        *(float4*)(B + (size_t)wid * 16 + j4 * 4) = o;
    }
}

// ---------------- edge head, U/V decomposition ----------------

__global__ __launch_bounds__(256) void uv_kernel(const float* __restrict__ H,
                                                 const float* __restrict__ Wf0,
                                                 const float* __restrict__ bf0,
                                                 float* __restrict__ U,
                                                 float* __restrict__ V, int N) {
    __shared__ float wf[512];
    __shared__ float bf[16];
    int tid = threadIdx.x;
    wf[tid] = Wf0[tid];
    wf[256 + tid] = Wf0[256 + tid];
    if (tid < 16) bf[tid] = bf0[tid];
    __syncthreads();
    int t = blockIdx.x * 256 + tid;
    int n = t >> 4, j = t & 15;
    if (n >= N) return;
    const float* hrow = H + (size_t)n * 16;
    float au = 0.f, av = 0.f;
    #pragma unroll
    for (int k = 0; k < 16; ++k) {
        float h = hrow[k];
        au = fmaf(h, wf[k * 16 + j], au);
        av = fmaf(h, wf[(16 + k) * 16 + j], av);
    }
    U[(size_t)n * 16 + j] = au;
    V[(size_t)n * 16 + j] = av + bf[j];
}

__global__ __launch_bounds__(256) void head2_kernel(const float* __restrict__ U,
                                                    const float* __restrict__ V,
                                                    const int* __restrict__ src,
                                                    const int* __restrict__ dst,
                                                    const float* __restrict__ Wf1,
                                                    const float* __restrict__ bf1,
                                                    float* __restrict__ out, int E) {
    __shared__ float w1[16];
    __shared__ float b1s;
    int tid = threadIdx.x;
    if (tid < 16) w1[tid] = Wf1[tid];
    if (tid == 16) b1s = bf1[0];
    __syncthreads();
    int e = blockIdx.x * 256 + tid;
    if (e >= E) return;
    int s = src[e], d = dst[e];
    const float4* us = (const float4*)(U + (size_t)s * 16);
    const float4* vd = (const float4*)(V + (size_t)d * 16);
    float o = b1s;
    #pragma unroll
    for (int i = 0; i < 4; ++i) {
        float4 u = us[i];
        float4 v = vd[i];
        o = fmaf(fmaxf(u.x + v.x, 0.f), w1[i * 4 + 0], o);
        o = fmaf(fmaxf(u.y + v.y, 0.f), w1[i * 4 + 1], o);
        o = fmaf(fmaxf(u.z + v.z, 0.f), w1[i * 4 + 2], o);
        o = fmaf(fmaxf(u.w + v.w, 0.f), w1[i * 4 + 3], o);
    }
    out[e] = o;
}

// ---------------- launch ----------------

extern "C" void kernel_launch(void* const* d_in, const int* in_sizes, int n_in,
                              void* d_out, int out_size, void* d_ws, size_t ws_size,
                              hipStream_t stream) {
    const float* x   = (const float*)d_in[0];
    const int*   ei  = (const int*)d_in[1];
    const float* W0  = (const float*)d_in[2];
    const float* b0  = (const float*)d_in[3];
    const float* W1  = (const float*)d_in[4];
    const float* b1  = (const float*)d_in[5];
    const float* W2  = (const float*)d_in[6];
    const float* b2  = (const float*)d_in[7];
    const float* Wf0 = (const float*)d_in[8];
    const float* bf0 = (const float*)d_in[9];
    const float* Wf1 = (const float*)d_in[10];
    const float* bf1 = (const float*)d_in[11];

    const int H  = 16;
    const int IN = in_sizes[2] / H;        // 495
    const int N  = in_sizes[0] / IN;       // 100000
    const int E  = in_sizes[1] / 2;        // 3200000
    const int NB = NW * WS;                // 100096 padded bins
    const int* src = ei;
    const int* dst = ei + E;

    char* ws = (char*)d_ws;
    size_t off = 0;
    auto alloc = [&](size_t bytes) {
        void* p = ws + off;
        off = (off + bytes + 255) & ~size_t(255);
        return p;
    };
    int*   hist       = (int*)alloc((size_t)N * 4);
    int*   row_ptr    = (int*)alloc((size_t)(N + 1) * 4);
    int*   partials   = (int*)alloc((size_t)((N + 255) / 256) * 4);
    float* dis        = (float*)alloc((size_t)N * 4);
    int*   src_sorted = (int*)alloc((size_t)E * 4);
    int*   part       = (int*)alloc((size_t)NW * NK * WS * 4);
    int*   wcnt       = (int*)alloc((size_t)NSL * NW * 4);
    int*   wofs       = (int*)alloc((size_t)NSL * NW * 4);
    int*   wstart     = (int*)alloc((size_t)(NW + 1) * 4);
    float* Ad         = (float*)alloc((size_t)N * 16 * 4);
    float* B          = (float*)alloc((size_t)N * 16 * 4);
    float* U          = (float*)alloc((size_t)N * 16 * 4);
    float* V          = (float*)alloc((size_t)N * 16 * 4);
    float* Apart      = (float*)alloc((size_t)4 * N * 16 * 4);
    // srcb/dstb alias Apart: build finishes before mm0 writes it (2*E == 4*N*16)
    int* srcb = (int*)Apart;
    int* dstb = srcb + E;

    int gE = (E + 255) / 256;
    int gN = (N + 255) / 256;

    // CSR build (no global atomics)
    bucket_count_kernel<<<NSL, 256, 0, stream>>>(dst, wcnt, E);
    scan_wofs_kernel<<<1, 512, 0, stream>>>(wcnt, wofs, wstart, E);
    bucket_scatter_kernel<<<NSL, 256, 0, stream>>>(src, dst, wofs, srcb, dstb, E);
    histpart2_kernel<<<NW * NK, 256, 0, stream>>>(dstb, wstart, part);
    scanslice2_kernel<<<(NB + 255) / 256, 256, 0, stream>>>(part, hist, N, NB);
    dis_kernel<<<gN, 256, 0, stream>>>(hist, dis, N);
    scan_part_kernel<<<gN, 256, 0, stream>>>(hist, partials, N);
    scan_top_kernel<<<1, 1024, 0, stream>>>(partials, gN);
    scan_final_kernel<<<gN, 256, 0, stream>>>(hist, partials, row_ptr, N);
    place2_kernel<<<NW * NK, 256, 0, stream>>>(srcb, dstb, wstart, row_ptr, part, src_sorted);

    dim3 g0((N + MM0_TM - 1) / MM0_TM, 4);
    mm0_kernel<<<g0, 256, 0, stream>>>(x, W0, Apart, N, IN);
    int nq = N * 16 / 4;
    reduce4_scale_kernel<<<(nq + 255) / 256, 256, 0, stream>>>(Apart, dis, Ad, nq, nq);

    prop_kernel<<<(N + 3) / 4, 256, 0, stream>>>(Ad, dis, row_ptr, src_sorted, b0, B, N);
    mm16_scale_kernel<<<(N * 16 + 255) / 256, 256, 0, stream>>>(B, W1, dis, Ad, N);
    prop_kernel<<<(N + 3) / 4, 256, 0, stream>>>(Ad, dis, row_ptr, src_sorted, b1, B, N);
    mm16_scale_kernel<<<(N * 16 + 255) / 256, 256, 0, stream>>>(B, W2, dis, Ad, N);
    prop_kernel<<<(N + 3) / 4, 256, 0, stream>>>(Ad, dis, row_ptr, src_sorted, b2, B, N);

    uv_kernel<<<(N * 16 + 255) / 256, 256, 0, stream>>>(B, Wf0, bf0, U, V, N);
    head2_kernel<<<gE, 256, 0, stream>>>(U, V, src, dst, Wf1, bf1, (float*)d_out, E);
}